// Round 6
// baseline (209.037 us; speedup 1.0000x reference)
//
#include <hip/hip_runtime.h>
#include <hip/hip_bf16.h>
#include <stdint.h>

typedef __bf16 bf16_t;
typedef float floatx4 __attribute__((ext_vector_type(4)));
typedef __bf16 bf16x8 __attribute__((ext_vector_type(8)));
typedef __bf16 bf16x4 __attribute__((ext_vector_type(4)));
typedef unsigned int uintx4 __attribute__((ext_vector_type(4)));

// scale = DH^-0.5 * log2(e), folded into Q at GEMM epilogue so softmax uses raw exp2
#define QSCALE 0.1803368801111204f

// -------------------- async global->LDS (16B) --------------------
__device__ __forceinline__ void gl2lds16(const bf16_t* g, bf16_t* l) {
    __builtin_amdgcn_global_load_lds(
        (const __attribute__((address_space(1))) unsigned int*)g,
        (__attribute__((address_space(3))) unsigned int*)l,
        16, 0, 0);
}

// pack two f32 -> one dword of 2 bf16 (scalar casts; compiler fuses well, m240)
__device__ __forceinline__ unsigned pk2(float lo, float hi) {
    unsigned short a = __builtin_bit_cast(unsigned short, (bf16_t)lo);
    unsigned short b = __builtin_bit_cast(unsigned short, (bf16_t)hi);
    return (unsigned)a | ((unsigned)b << 16);
}

// -------------------- fp32 -> bf16 convert (x and W fused) --------------------
__global__ __launch_bounds__(256) void convert_kernel(const float* __restrict__ x,
                                                      bf16_t* __restrict__ xb,
                                                      const float* __restrict__ w,
                                                      bf16_t* __restrict__ wb,
                                                      int nx4) {   // x chunks; W chunks follow
    int i = blockIdx.x * 256 + threadIdx.x;
    const float* in; bf16_t* out; int j;
    if (i < nx4) { in = x; out = xb; j = i; }
    else         { in = w; out = wb; j = i - nx4; }
    float4 v = ((const float4*)in)[j];
    bf16x4 o;
    o.x = (bf16_t)v.x; o.y = (bf16_t)v.y; o.z = (bf16_t)v.z; o.w = (bf16_t)v.w;
    ((bf16x4*)out)[j] = o;
}

// -------------------- QKV projection GEMM (gemm_bt) --------------------
// R10 structure (unchanged in R11): 128x64 tile, double-buffered LDS, one
// barrier per K-step, staging issued before compute, XCD swizzle.
__global__ __launch_bounds__(256, 3) void qkv_gemm(const bf16_t* __restrict__ X,   // [8192][512]
                                                   const bf16_t* __restrict__ W,   // [1536][512]
                                                   bf16_t* __restrict__ Q,         // [32][2048][64] (pre-scaled)
                                                   bf16_t* __restrict__ K,         // [32][2048][64]
                                                   bf16_t* __restrict__ Vt)        // [32][64][2048]
{
    __shared__ bf16_t As[2][128 * 64];   // 2 x 16 KB
    __shared__ bf16_t Bs[2][64 * 64];    // 2 x  8 KB   (total 48 KB -> 3 blocks/CU)

    const int tid  = threadIdx.x;
    const int wave = tid >> 6;
    const int lane = tid & 63;
    const int quad = lane >> 4;
    const int lrow = lane & 15;
    const int t7g  = lrow & 7;      // = row&7 of every fragment row this lane touches
    const int wbase = tid & 192;    // wave*64, wave-uniform

    int raw = blockIdx.x;
    int xcd = raw & 7;
    int idx = raw >> 3;
    int bx  = xcd * 8 + idx / 24;
    int by  = idx - (idx / 24) * 24;
    const int bm0 = bx * 128;
    const int bn0 = by * 64;
    const int mw = (wave >> 1) * 64;
    const int nw = (wave & 1) * 32;

    floatx4 acc[4][2];
#pragma unroll
    for (int i = 0; i < 4; i++)
#pragma unroll
        for (int j = 0; j < 2; j++) acc[i][j] = (floatx4)0.0f;

    const bf16_t* xb  = X + (size_t)bm0 * 512;
    const bf16_t* wbp = W + (size_t)bn0 * 512;
    const bf16_t* srcA[4];
    const bf16_t* srcB[2];
#pragma unroll
    for (int r = 0; r < 4; ++r) {
        int c = r * 256 + tid;
        int row = c >> 3, kc = c & 7;
        int skc = kc ^ (row & 7);              // swizzled source chunk
        srcA[r] = xb + (size_t)row * 512 + skc * 8;
    }
#pragma unroll
    for (int r = 0; r < 2; ++r) {
        int c = r * 256 + tid;
        int row = c >> 3, kc = c & 7;
        int skc = kc ^ (row & 7);
        srcB[r] = wbp + (size_t)row * 512 + skc * 8;
    }

    auto STAGE = [&](int bufI, int k0) {
#pragma unroll
        for (int r = 0; r < 4; ++r)
            gl2lds16(srcA[r] + k0, As[bufI] + (size_t)(r * 256 + wbase) * 8);
#pragma unroll
        for (int r = 0; r < 2; ++r)
            gl2lds16(srcB[r] + k0, Bs[bufI] + (size_t)(r * 256 + wbase) * 8);
    };

    STAGE(0, 0);

#pragma unroll 1
    for (int kb = 0; kb < 8; ++kb) {
        const int buf = kb & 1;
        __syncthreads();                 // drains vmcnt: tile kb staged; prev compute done
        if (kb < 7) STAGE(buf ^ 1, (kb + 1) * 64);

        const bf16_t* as = As[buf];
        const bf16_t* bs = Bs[buf];
#pragma unroll
        for (int ks = 0; ks < 2; ++ks) {
            bf16x8 af[4], bfr[2];
#pragma unroll
            for (int mi = 0; mi < 4; mi++)
                af[mi] = *(const bf16x8*)(as + (mw + mi * 16 + lrow) * 64 + (((ks * 4 + quad) ^ t7g) << 3));
#pragma unroll
            for (int ni = 0; ni < 2; ni++)
                bfr[ni] = *(const bf16x8*)(bs + (nw + ni * 16 + lrow) * 64 + (((ks * 4 + quad) ^ t7g) << 3));
            __builtin_amdgcn_s_setprio(1);
#pragma unroll
            for (int mi = 0; mi < 4; mi++)
#pragma unroll
                for (int ni = 0; ni < 2; ni++)
                    acc[mi][ni] = __builtin_amdgcn_mfma_f32_16x16x32_bf16(af[mi], bfr[ni], acc[mi][ni], 0, 0, 0);
            __builtin_amdgcn_s_setprio(0);
        }
    }

    // epilogue: C/D layout col=lane&15, row=quad*4+reg  [verified m89]
#pragma unroll
    for (int mi = 0; mi < 4; mi++) {
        int mbase = bm0 + mw + mi * 16 + quad * 4;
        int b = mbase >> 11, n = mbase & 2047;   // r never crosses batch boundary (mbase%4==0)
#pragma unroll
        for (int ni = 0; ni < 2; ni++) {
            int o = bn0 + nw + ni * 16 + lrow;
            int s  = o >> 9;
            int h  = (o >> 6) & 7;
            int dh = o & 63;
            int bh = b * 8 + h;
            if (s == 2) {
                bf16x4 pv;
#pragma unroll
                for (int r = 0; r < 4; r++) pv[r] = (bf16_t)acc[mi][ni][r];
                *(bf16x4*)(Vt + ((size_t)bh * 64 + dh) * 2048 + n) = pv;   // 8B packed
            } else if (s == 0) {
#pragma unroll
                for (int r = 0; r < 4; r++)
                    Q[((size_t)bh * 2048 + n + r) * 64 + dh] = (bf16_t)(acc[mi][ni][r] * QSCALE);
            } else {
#pragma unroll
                for (int r = 0; r < 4; r++)
                    K[((size_t)bh * 2048 + n + r) * 64 + dh] = (bf16_t)acc[mi][ni][r];
            }
        }
    }
}

// -------------------- flash attention --------------------
// R11: LDS-FREE main loop. R10 counters: MfmaUtil 25 / VALU 47 / HBM 6% -- no
// pipe saturated; wall 4350cy/kt vs ~2000-2800cy packed work => barrier convoy
// + shared LDS pipe (16 waves x 10 b128 x 12cy ~ 1920cy/CU/kt) are the bound.
// Post-XCD-swizzle K/V is L2-resident (FETCH 12.3MB), so skip LDS entirely:
// each wave global_loads its 8 fragments (4 K + 4 V; 16x64B segments each,
// coalesced) straight from L2 every kt. No staging, no ds_read, NO BARRIER in
// the loop -- 16 free-running waves, TLP hides L2 latency. Cost: 2x L2 re-read
// (qhalf duplication; ~2300cy/CU/kt L2-BW bound < 4350 today, L1 may absorb).
// De-swizzle identity: LDS read chunk X^t7 held global chunk X, so direct
// global reads use chunk X addresses; pfrag/permlane/MFMA math is unchanged
// from the harness-verified R8/R10 kernel.
__global__ __launch_bounds__(256, 4) void flash_attn(const bf16_t* __restrict__ Q,   // [32][2048][64], pre-scaled
                                                     const bf16_t* __restrict__ K,   // [32][2048][64]
                                                     const bf16_t* __restrict__ Vt,  // [32][64][2048]
                                                     float* __restrict__ Out)        // [4][2048][512]
{
    __shared__ float red[2 * 2048 + 64];   // 16.25 KB, final reduction only

    const int tid  = threadIdx.x;
    const int wave = tid >> 6;
    const int lane = tid & 63;
    const int quad = lane >> 4;
    const int c    = lane & 15;
    const int qhalf = wave >> 1;   // which 32 q-rows
    const int khalf = wave & 1;    // which 32 keys of each 64-key tile

    // XCD swizzle (R9-proven): XCD (raw&7) owns bh group of 4
    int raw = blockIdx.x + (blockIdx.y << 5);
    int swz = (raw & 7) * 128 + (raw >> 3);
    const int qt = swz & 31;
    const int bh = swz >> 5;
    const int b = bh >> 3, h = bh & 7;

    // K A-operand row map: m=c -> key row bw = quad-bit-swapped c (bijective 0..15)
    const int bw = ((c & 4) << 1) | ((c & 8) >> 1) | (c & 3);

    // Q fragments (B-operand: n=lane&15=q-col, k=quad*8+j), shifted-query source row.
    bf16x8 qf[2][2];
#pragma unroll
    for (int mt = 0; mt < 2; ++mt) {
        int qg  = qt * 64 + qhalf * 32 + mt * 16 + c;
        int src = (qg == 0) ? 0 : qg - 1;
        const bf16_t* qbase = Q + ((size_t)bh * 2048 + src) * 64;
        qf[mt][0] = *(const bf16x8*)(qbase + quad * 8);
        qf[mt][1] = *(const bf16x8*)(qbase + 32 + quad * 8);
    }

    floatx4 o[2][4];
#pragma unroll
    for (int mt = 0; mt < 2; ++mt)
#pragma unroll
        for (int i = 0; i < 4; i++) o[mt][i] = (floatx4)0.0f;
    float lacc[2] = {0.f, 0.f};

    // per-lane global fragment bases (kt=0); kk advances 4096 elem/kt, vv 64
    const bf16_t* kk = K + ((size_t)bh * 2048 + khalf * 32 + bw) * 64 + quad * 8;
    const bf16_t* vv = Vt + ((size_t)bh * 64 + c) * 2048 + khalf * 32 + quad * 8;

#pragma unroll 1
    for (int kt = 0; kt < 32; ++kt) {
        // K fragments: nt0/nt1 rows (+0 / +1024 elems), d 0-31 / 32-63 (+0/+32)
        bf16x8 kf00 = *(const bf16x8*)(kk);
        bf16x8 kf01 = *(const bf16x8*)(kk + 32);
        bf16x8 kf10 = *(const bf16x8*)(kk + 1024);
        bf16x8 kf11 = *(const bf16x8*)(kk + 1056);

        // S^T = K * Q^T : D[key][q=c]
        floatx4 s[2][2];
        __builtin_amdgcn_s_setprio(1);
#pragma unroll
        for (int mt = 0; mt < 2; ++mt) {
            floatx4 t0 = (floatx4)0.0f;
            t0 = __builtin_amdgcn_mfma_f32_16x16x32_bf16(kf00, qf[mt][0], t0, 0, 0, 0);
            t0 = __builtin_amdgcn_mfma_f32_16x16x32_bf16(kf01, qf[mt][1], t0, 0, 0, 0);
            s[mt][0] = t0;
            floatx4 t1 = (floatx4)0.0f;
            t1 = __builtin_amdgcn_mfma_f32_16x16x32_bf16(kf10, qf[mt][0], t1, 0, 0, 0);
            t1 = __builtin_amdgcn_mfma_f32_16x16x32_bf16(kf11, qf[mt][1], t1, 0, 0, 0);
            s[mt][1] = t1;
        }
        __builtin_amdgcn_s_setprio(0);

        // V fragments issued here: latency hides under softmax VALU below
        bf16x8 vf0 = *(const bf16x8*)(vv);
        bf16x8 vf1 = *(const bf16x8*)(vv + 16 * 2048);
        bf16x8 vf2 = *(const bf16x8*)(vv + 32 * 2048);
        bf16x8 vf3 = *(const bf16x8*)(vv + 48 * 2048);
        kk += 4096; vv += 64;

        // P = exp2(S); per-lane partial row sum (q=c); in-register PV A-frags
        bf16x8 pfrag[2];
#pragma unroll
        for (int mt = 0; mt < 2; ++mt) {
            float pe[2][4];
#pragma unroll
            for (int nt = 0; nt < 2; ++nt)
#pragma unroll
                for (int r = 0; r < 4; ++r) {
                    float p = __builtin_amdgcn_exp2f(s[mt][nt][r]);
                    lacc[mt] += p;
                    pe[nt][r] = p;
                }
            unsigned A0 = pk2(pe[0][0], pe[0][1]);
            unsigned A1 = pk2(pe[0][2], pe[0][3]);
            unsigned B0 = pk2(pe[1][0], pe[1][1]);
            unsigned B1 = pk2(pe[1][2], pe[1][3]);
            auto r0 = __builtin_amdgcn_permlane32_swap((int)A0, (int)B0, false, false);
            auto r1 = __builtin_amdgcn_permlane32_swap((int)A1, (int)B1, false, false);
            uintx4 fd;
            fd.x = (unsigned)r0[0];
            fd.y = (unsigned)r1[0];
            fd.z = (unsigned)r0[1];
            fd.w = (unsigned)r1[1];
            pfrag[mt] = __builtin_bit_cast(bf16x8, fd);
        }

        // O += P * V (contraction over this wave's 32 keys, all operands in regs)
        __builtin_amdgcn_s_setprio(1);
        o[0][0] = __builtin_amdgcn_mfma_f32_16x16x32_bf16(pfrag[0], vf0, o[0][0], 0, 0, 0);
        o[1][0] = __builtin_amdgcn_mfma_f32_16x16x32_bf16(pfrag[1], vf0, o[1][0], 0, 0, 0);
        o[0][1] = __builtin_amdgcn_mfma_f32_16x16x32_bf16(pfrag[0], vf1, o[0][1], 0, 0, 0);
        o[1][1] = __builtin_amdgcn_mfma_f32_16x16x32_bf16(pfrag[1], vf1, o[1][1], 0, 0, 0);
        o[0][2] = __builtin_amdgcn_mfma_f32_16x16x32_bf16(pfrag[0], vf2, o[0][2], 0, 0, 0);
        o[1][2] = __builtin_amdgcn_mfma_f32_16x16x32_bf16(pfrag[1], vf2, o[1][2], 0, 0, 0);
        o[0][3] = __builtin_amdgcn_mfma_f32_16x16x32_bf16(pfrag[0], vf3, o[0][3], 0, 0, 0);
        o[1][3] = __builtin_amdgcn_mfma_f32_16x16x32_bf16(pfrag[1], vf3, o[1][3], 0, 0, 0);
        __builtin_amdgcn_s_setprio(0);
    }

    // in-wave reduction over the 4 key-quads: butterfly xor16 + xor32
#pragma unroll
    for (int mt = 0; mt < 2; ++mt) {
        lacc[mt] += __shfl_xor(lacc[mt], 16, 64);
        lacc[mt] += __shfl_xor(lacc[mt], 32, 64);
    }

    // cross-khalf reduction of partial O and l via LDS (once)
    float* obuf = red;               // 2 qhalf x 2048 f32 = 16 KB
    float* lbuf = red + 4096;        // 2 qhalf x 32 f32
    if (khalf == 1) {
#pragma unroll
        for (int mt = 0; mt < 2; ++mt)
#pragma unroll
            for (int sub = 0; sub < 4; ++sub)
                *(floatx4*)(obuf + qhalf * 2048 + (mt * 4 + sub) * 256 + lane * 4) = o[mt][sub];
        if (lane < 16) {             // quad0 lanes: lacc holds l(q = mt*16+c)
#pragma unroll
            for (int mt = 0; mt < 2; ++mt)
                lbuf[qhalf * 32 + mt * 16 + c] = lacc[mt];
        }
    }
    __syncthreads();
    if (khalf == 0) {
#pragma unroll
        for (int mt = 0; mt < 2; ++mt)
#pragma unroll
            for (int sub = 0; sub < 4; ++sub)
                o[mt][sub] += *(const floatx4*)(obuf + qhalf * 2048 + (mt * 4 + sub) * 256 + lane * 4);
#pragma unroll
        for (int mt = 0; mt < 2; ++mt)
            lacc[mt] += lbuf[qhalf * 32 + mt * 16 + c];

        // epilogue: out[b][n][h*64 + d] = o / l ; l for row q=quad*4+r via shfl
        float* ob = Out + (size_t)b * 2048 * 512 + (size_t)h * 64;
#pragma unroll
        for (int mt = 0; mt < 2; ++mt) {
            int n0 = qt * 64 + qhalf * 32 + mt * 16 + quad * 4;
#pragma unroll
            for (int r = 0; r < 4; r++) {
                float lr = __shfl(lacc[mt], quad * 4 + r, 64);
                float inv = 1.0f / lr;
                float* orow = ob + (size_t)(n0 + r) * 512;
#pragma unroll
                for (int sub = 0; sub < 4; ++sub)
                    orow[sub * 16 + c] = o[mt][sub][r] * inv;
            }
        }
    }
}

// -------------------- launch --------------------
extern "C" void kernel_launch(void* const* d_in, const int* in_sizes, int n_in,
                              void* d_out, int out_size, void* d_ws, size_t ws_size,
                              hipStream_t stream) {
    const float* x = (const float*)d_in[0];   // [4,2048,512]
    const float* w = (const float*)d_in[1];   // [1536,512]
    float* out = (float*)d_out;               // [4,2048,512]

    char* ws = (char*)d_ws;
    bf16_t* xb = (bf16_t*)(ws);                       //  8 MB
    bf16_t* wb = (bf16_t*)(ws + 8388608);             //  1.5 MB
    bf16_t* q  = (bf16_t*)(ws + 9961472);             //  8 MB
    bf16_t* k  = (bf16_t*)(ws + 18350080);            //  8 MB
    bf16_t* vt = (bf16_t*)(ws + 26738688);            //  8 MB (end 33.5 MB)

    convert_kernel<<<4864, 256, 0, stream>>>(x, xb, w, wb, 1048576);
    qkv_gemm<<<1536, 256, 0, stream>>>(xb, wb, q, k, vt);
    flash_attn<<<dim3(32, 32), 256, 0, stream>>>(q, k, vt, out);
}

// Round 8
// 143.848 us; speedup vs baseline: 1.4532x; 1.4532x over previous
//
#include <hip/hip_runtime.h>
#include <hip/hip_bf16.h>
#include <stdint.h>

typedef __bf16 bf16_t;
typedef float floatx4 __attribute__((ext_vector_type(4)));
typedef __bf16 bf16x8 __attribute__((ext_vector_type(8)));
typedef __bf16 bf16x4 __attribute__((ext_vector_type(4)));
typedef unsigned int uintx4 __attribute__((ext_vector_type(4)));

// scale = DH^-0.5 * log2(e), folded into Q at GEMM epilogue so softmax uses raw exp2
#define QSCALE 0.1803368801111204f

// -------------------- async global->LDS (16B) --------------------
__device__ __forceinline__ void gl2lds16(const bf16_t* g, bf16_t* l) {
    __builtin_amdgcn_global_load_lds(
        (const __attribute__((address_space(1))) unsigned int*)g,
        (__attribute__((address_space(3))) unsigned int*)l,
        16, 0, 0);
}

// pack two f32 -> one dword of 2 bf16
__device__ __forceinline__ unsigned pk2(float lo, float hi) {
    unsigned short a = __builtin_bit_cast(unsigned short, (bf16_t)lo);
    unsigned short b = __builtin_bit_cast(unsigned short, (bf16_t)hi);
    return (unsigned)a | ((unsigned)b << 16);
}

// -------------------- fp32 -> bf16 convert (x and W fused) --------------------
__global__ __launch_bounds__(256) void convert_kernel(const float* __restrict__ x,
                                                      bf16_t* __restrict__ xb,
                                                      const float* __restrict__ w,
                                                      bf16_t* __restrict__ wb,
                                                      int nx4) {   // x chunks; W chunks follow
    int i = blockIdx.x * 256 + threadIdx.x;
    const float* in; bf16_t* out; int j;
    if (i < nx4) { in = x; out = xb; j = i; }
    else         { in = w; out = wb; j = i - nx4; }
    float4 v = ((const float4*)in)[j];
    bf16x4 o;
    o.x = (bf16_t)v.x; o.y = (bf16_t)v.y; o.z = (bf16_t)v.z; o.w = (bf16_t)v.w;
    ((bf16x4*)out)[j] = o;
}

// -------------------- QKV projection GEMM (gemm_bt) --------------------
// R10 structure (unchanged): 128x64 tile, double-buffered LDS, one barrier per
// K-step, staging issued before compute, XCD swizzle.
__global__ __launch_bounds__(256, 3) void qkv_gemm(const bf16_t* __restrict__ X,   // [8192][512]
                                                   const bf16_t* __restrict__ W,   // [1536][512]
                                                   bf16_t* __restrict__ Q,         // [32][2048][64] (pre-scaled)
                                                   bf16_t* __restrict__ K,         // [32][2048][64]
                                                   bf16_t* __restrict__ Vt)        // [32][64][2048]
{
    __shared__ bf16_t As[2][128 * 64];   // 2 x 16 KB
    __shared__ bf16_t Bs[2][64 * 64];    // 2 x  8 KB   (total 48 KB -> 3 blocks/CU)

    const int tid  = threadIdx.x;
    const int wave = tid >> 6;
    const int lane = tid & 63;
    const int quad = lane >> 4;
    const int lrow = lane & 15;
    const int t7g  = lrow & 7;      // = row&7 of every fragment row this lane touches
    const int wbase = tid & 192;    // wave*64, wave-uniform

    int raw = blockIdx.x;
    int xcd = raw & 7;
    int idx = raw >> 3;
    int bx  = xcd * 8 + idx / 24;
    int by  = idx - (idx / 24) * 24;
    const int bm0 = bx * 128;
    const int bn0 = by * 64;
    const int mw = (wave >> 1) * 64;
    const int nw = (wave & 1) * 32;

    floatx4 acc[4][2];
#pragma unroll
    for (int i = 0; i < 4; i++)
#pragma unroll
        for (int j = 0; j < 2; j++) acc[i][j] = (floatx4)0.0f;

    const bf16_t* xb  = X + (size_t)bm0 * 512;
    const bf16_t* wbp = W + (size_t)bn0 * 512;
    const bf16_t* srcA[4];
    const bf16_t* srcB[2];
#pragma unroll
    for (int r = 0; r < 4; ++r) {
        int c = r * 256 + tid;
        int row = c >> 3, kc = c & 7;
        int skc = kc ^ (row & 7);              // swizzled source chunk
        srcA[r] = xb + (size_t)row * 512 + skc * 8;
    }
#pragma unroll
    for (int r = 0; r < 2; ++r) {
        int c = r * 256 + tid;
        int row = c >> 3, kc = c & 7;
        int skc = kc ^ (row & 7);
        srcB[r] = wbp + (size_t)row * 512 + skc * 8;
    }

    auto STAGE = [&](int bufI, int k0) {
#pragma unroll
        for (int r = 0; r < 4; ++r)
            gl2lds16(srcA[r] + k0, As[bufI] + (size_t)(r * 256 + wbase) * 8);
#pragma unroll
        for (int r = 0; r < 2; ++r)
            gl2lds16(srcB[r] + k0, Bs[bufI] + (size_t)(r * 256 + wbase) * 8);
    };

    STAGE(0, 0);

#pragma unroll 1
    for (int kb = 0; kb < 8; ++kb) {
        const int buf = kb & 1;
        __syncthreads();                 // drains vmcnt: tile kb staged; prev compute done
        if (kb < 7) STAGE(buf ^ 1, (kb + 1) * 64);

        const bf16_t* as = As[buf];
        const bf16_t* bs = Bs[buf];
#pragma unroll
        for (int ks = 0; ks < 2; ++ks) {
            bf16x8 af[4], bfr[2];
#pragma unroll
            for (int mi = 0; mi < 4; mi++)
                af[mi] = *(const bf16x8*)(as + (mw + mi * 16 + lrow) * 64 + (((ks * 4 + quad) ^ t7g) << 3));
#pragma unroll
            for (int ni = 0; ni < 2; ni++)
                bfr[ni] = *(const bf16x8*)(bs + (nw + ni * 16 + lrow) * 64 + (((ks * 4 + quad) ^ t7g) << 3));
            __builtin_amdgcn_s_setprio(1);
#pragma unroll
            for (int mi = 0; mi < 4; mi++)
#pragma unroll
                for (int ni = 0; ni < 2; ni++)
                    acc[mi][ni] = __builtin_amdgcn_mfma_f32_16x16x32_bf16(af[mi], bfr[ni], acc[mi][ni], 0, 0, 0);
            __builtin_amdgcn_s_setprio(0);
        }
    }

    // epilogue: C/D layout col=lane&15, row=quad*4+reg  [verified m89]
#pragma unroll
    for (int mi = 0; mi < 4; mi++) {
        int mbase = bm0 + mw + mi * 16 + quad * 4;
        int b = mbase >> 11, n = mbase & 2047;
#pragma unroll
        for (int ni = 0; ni < 2; ni++) {
            int o = bn0 + nw + ni * 16 + lrow;
            int s  = o >> 9;
            int h  = (o >> 6) & 7;
            int dh = o & 63;
            int bh = b * 8 + h;
            if (s == 2) {
                bf16x4 pv;
#pragma unroll
                for (int r = 0; r < 4; r++) pv[r] = (bf16_t)acc[mi][ni][r];
                *(bf16x4*)(Vt + ((size_t)bh * 64 + dh) * 2048 + n) = pv;   // 8B packed
            } else if (s == 0) {
#pragma unroll
                for (int r = 0; r < 4; r++)
                    Q[((size_t)bh * 2048 + n + r) * 64 + dh] = (bf16_t)(acc[mi][ni][r] * QSCALE);
            } else {
#pragma unroll
                for (int r = 0; r < 4; r++)
                    K[((size_t)bh * 2048 + n + r) * 64 + dh] = (bf16_t)acc[mi][ni][r];
            }
        }
    }
}

// -------------------- flash attention --------------------
// R12 (resubmit, compile fix): pair-of-tiles + key-quarter waves. R11 post-
// mortem: global per-lane gathers are dead (16-seg/instr, 127us); LDS staging
// is mandatory. R8's floor analysis: LDS bytes/CU ~6.1MB -> ~23us of 55.6.
// Halve LDS reads via q-amortization at CONSTANT block shape: process kt-tiles
// in PAIRS (t0,t1); 4 waves, wave w owns keys w*16..+15 of EACH tile (32
// contraction keys/pair) x all 64 q. Per wave-kt: kf 2 + vf 2 b128 = 4KB (R8:
// 8KB). PV uses R8's verified bw-map + permlane32_swap with (A0,A1)=t0,
// (B0,B1)=t1 (pair = two tiles instead of two 16-key groups; same lane
// algebra). Q in regs (32 VGPR). Barrier rate = 1/kt (same). Single
// pair-buffer (sync;stage;sync;compute), 3 blocks/CU decorrelation covers
// stage latency (m97 pattern). 33KB LDS; VGPR ~160 -> bounds(256,3).
__global__ __launch_bounds__(256, 3) void flash_attn(const bf16_t* __restrict__ Q,   // [32][2048][64], pre-scaled
                                                     const bf16_t* __restrict__ K,   // [32][2048][64]
                                                     const bf16_t* __restrict__ Vt,  // [32][64][2048]
                                                     float* __restrict__ Out)        // [4][2048][512]
{
    __shared__ __align__(16) bf16_t smem[4 * 4096];   // Ks[2]=smem, Vs[2]=smem+8192 (32 KB)
    __shared__ float lbuf[4 * 64];                    // per-wave l partials (1 KB)

    bf16_t* Ks = smem;           // [t][64key][64d]
    bf16_t* Vs = smem + 8192;    // [t][64d][64key]

    const int tid  = threadIdx.x;
    const int w    = tid >> 6;   // key-group 0..3 (keys w*16..+15 of each tile)
    const int lane = tid & 63;
    const int quad = lane >> 4;
    const int c    = lane & 15;
    const int qt = blockIdx.x;
    const int bh = blockIdx.y;
    const int b = bh >> 3, hd = bh & 7;

    // A-operand row map (R8-verified): m=c -> key row bw; lane(quad) ends up
    // holding keys {0-3,8-11,4-7,12-15}[quad] within its 16-key group.
    const int bw  = ((c & 4) << 1) | ((c & 8) >> 1) | (c & 3);
    const int bw7 = bw & 7;

    // Q fragments (B-operand: n=c=q within group g, k=quad*8+j -> d=h*32+quad*8+j)
    bf16x8 qf[4][2];
#pragma unroll
    for (int g = 0; g < 4; ++g) {
        int qg  = qt * 64 + g * 16 + c;
        int src = (qg == 0) ? 0 : qg - 1;            // shifted query
        const bf16_t* qbase = Q + ((size_t)bh * 2048 + src) * 64;
#pragma unroll
        for (int h = 0; h < 2; ++h)
            qf[g][h] = *(const bf16x8*)(qbase + h * 32 + quad * 8);
    }

    floatx4 O[4][4];   // [q-group g][d-group dg]; O(q=g*16+quad*4+r, d=dg*16+c)
#pragma unroll
    for (int g = 0; g < 4; ++g)
#pragma unroll
        for (int dg = 0; dg < 4; ++dg) O[g][dg] = (floatx4)0.0f;
    float lacc[4] = {0.f, 0.f, 0.f, 0.f};

    const bf16_t* kb = K + ((size_t)bh * 2048) * 64;
    const bf16_t* vb = Vt + ((size_t)bh * 64) * 2048;

    // hoisted staging geometry: 512 chunks per 64x64 tile; thread covers 2
    const int ch0 = w * 64 + lane;
    const int r0s = ch0 >> 3, c0s = (ch0 & 7) ^ (r0s & 7);
    const int ch1 = 256 + ch0;
    const int r1s = ch1 >> 3, c1s = (ch1 & 7) ^ (r1s & 7);
    const bf16_t* gk0 = kb + r0s * 64 + c0s * 8;          // + kt*4096
    const bf16_t* gk1 = kb + r1s * 64 + c1s * 8;
    const bf16_t* gv0 = vb + (size_t)r0s * 2048 + c0s * 8; // + kt*64
    const bf16_t* gv1 = vb + (size_t)r1s * 2048 + c1s * 8;
    const int woff = w * 512;    // wave-uniform LDS dst (chunks part*256+w*64)

    // hoisted fragment read offsets (elements)
    const int krow = w * 16 + bw;
    int koff[2][2];
#pragma unroll
    for (int t = 0; t < 2; ++t)
#pragma unroll
        for (int h = 0; h < 2; ++h)
            koff[t][h] = t * 4096 + krow * 64 + (((h * 4 + quad) ^ bw7) << 3);
    int voff[4];
#pragma unroll
    for (int dg = 0; dg < 4; ++dg)
        voff[dg] = (quad >> 1) * 4096 + (dg * 16 + c) * 64 + (((2 * w + (quad & 1)) ^ (c & 7)) << 3);

#pragma unroll 1
    for (int p = 0; p < 16; ++p) {
        __syncthreads();   // all waves done reading previous pair
        // stage pair p: tiles 2p, 2p+1 (K and V), 8 gl2lds per thread
#pragma unroll
        for (int t = 0; t < 2; ++t) {
            const int kt = 2 * p + t;
            gl2lds16(gk0 + (size_t)kt * 4096, Ks + t * 4096 + woff);
            gl2lds16(gk1 + (size_t)kt * 4096, Ks + t * 4096 + 2048 + woff);
            gl2lds16(gv0 + kt * 64,           Vs + t * 4096 + woff);
            gl2lds16(gv1 + kt * 64,           Vs + t * 4096 + 2048 + woff);
        }
        __syncthreads();   // implicit vmcnt(0): pair staged and visible

        // kf: A-frags K[16keys][64d] for both tiles
        bf16x8 kf00 = *(const bf16x8*)(Ks + koff[0][0]);
        bf16x8 kf01 = *(const bf16x8*)(Ks + koff[0][1]);
        bf16x8 kf10 = *(const bf16x8*)(Ks + koff[1][0]);
        bf16x8 kf11 = *(const bf16x8*)(Ks + koff[1][1]);

        // per q-group: QK^T both tiles -> exp2 -> pack -> permlane -> PV A-frag
        bf16x8 pfrag[4];
#pragma unroll
        for (int g = 0; g < 4; ++g) {
            __builtin_amdgcn_s_setprio(1);
            floatx4 s0 = (floatx4)0.0f, s1 = (floatx4)0.0f;
            s0 = __builtin_amdgcn_mfma_f32_16x16x32_bf16(kf00, qf[g][0], s0, 0, 0, 0);
            s0 = __builtin_amdgcn_mfma_f32_16x16x32_bf16(kf01, qf[g][1], s0, 0, 0, 0);
            s1 = __builtin_amdgcn_mfma_f32_16x16x32_bf16(kf10, qf[g][0], s1, 0, 0, 0);
            s1 = __builtin_amdgcn_mfma_f32_16x16x32_bf16(kf11, qf[g][1], s1, 0, 0, 0);
            __builtin_amdgcn_s_setprio(0);

            float p0[4], p1[4];
#pragma unroll
            for (int r = 0; r < 4; ++r) {
                p0[r] = __builtin_amdgcn_exp2f(s0[r]);
                p1[r] = __builtin_amdgcn_exp2f(s1[r]);
                lacc[g] += p0[r] + p1[r];
            }
            unsigned A0 = pk2(p0[0], p0[1]);
            unsigned A1 = pk2(p0[2], p0[3]);
            unsigned B0 = pk2(p1[0], p1[1]);
            unsigned B1 = pk2(p1[2], p1[3]);
            auto r0 = __builtin_amdgcn_permlane32_swap((int)A0, (int)B0, false, false);
            auto r1 = __builtin_amdgcn_permlane32_swap((int)A1, (int)B1, false, false);
            uintx4 fd;
            fd.x = (unsigned)r0[0];
            fd.y = (unsigned)r1[0];
            fd.z = (unsigned)r0[1];
            fd.w = (unsigned)r1[1];
            pfrag[g] = __builtin_bit_cast(bf16x8, fd);
        }

        // PV: O[g][dg] += P * V (contraction over 32 pair-keys; k=quad*8+j maps
        // quad0,1 -> t0 keys, quad2,3 -> t1 keys; vf reads match via quad>>1 buf)
        __builtin_amdgcn_s_setprio(1);
#pragma unroll
        for (int dg = 0; dg < 4; ++dg) {
            bf16x8 vf = *(const bf16x8*)(Vs + voff[dg]);
#pragma unroll
            for (int g = 0; g < 4; ++g)
                O[g][dg] = __builtin_amdgcn_mfma_f32_16x16x32_bf16(pfrag[g], vf, O[g][dg], 0, 0, 0);
        }
        __builtin_amdgcn_s_setprio(0);
    }

    // ---- reductions ----
    // in-wave l: sum the 4 key-quads -> every lane holds l_w(q=g*16+c)
#pragma unroll
    for (int g = 0; g < 4; ++g) {
        lacc[g] += __shfl_xor(lacc[g], 16, 64);
        lacc[g] += __shfl_xor(lacc[g], 32, 64);
    }
    if (lane < 16) {
#pragma unroll
        for (int g = 0; g < 4; ++g)
            lbuf[w * 64 + g * 16 + lane] = lacc[g];
    }

    // cross-wave O: tree through LDS (reuse Ks/Vs = 32 KB = 2 slots x 16 KB)
    // slot layout: slot s : [(g*4+dg)*256 + lane*4]
    float* obuf = (float*)smem;
    __syncthreads();   // main-loop reads done; lbuf written
    if (w & 1) {       // waves 1,3 write
        float* dst = obuf + (w >> 1) * 4096;
#pragma unroll
        for (int g = 0; g < 4; ++g)
#pragma unroll
            for (int dg = 0; dg < 4; ++dg)
                *(floatx4*)(dst + (g * 4 + dg) * 256 + lane * 4) = O[g][dg];
    }
    __syncthreads();
    if (!(w & 1)) {    // waves 0,2 accumulate partner's partial
        const float* src = obuf + (w >> 1) * 4096;
#pragma unroll
        for (int g = 0; g < 4; ++g)
#pragma unroll
            for (int dg = 0; dg < 4; ++dg)
                O[g][dg] += *(const floatx4*)(src + (g * 4 + dg) * 256 + lane * 4);
    }
    __syncthreads();
    if (w == 2) {      // wave 2 writes its sum into slot 1
        float* dst = obuf + 4096;
#pragma unroll
        for (int g = 0; g < 4; ++g)
#pragma unroll
            for (int dg = 0; dg < 4; ++dg)
                *(floatx4*)(dst + (g * 4 + dg) * 256 + lane * 4) = O[g][dg];
    }
    __syncthreads();
    if (w == 0) {      // wave 0: final sum, divide, store
        const float* src = obuf + 4096;
#pragma unroll
        for (int g = 0; g < 4; ++g)
#pragma unroll
            for (int dg = 0; dg < 4; ++dg)
                O[g][dg] += *(const floatx4*)(src + (g * 4 + dg) * 256 + lane * 4);

        float* ob = Out + (size_t)b * 2048 * 512 + (size_t)hd * 64;
#pragma unroll
        for (int g = 0; g < 4; ++g) {
            float lt = lbuf[0 * 64 + g * 16 + c] + lbuf[1 * 64 + g * 16 + c]
                     + lbuf[2 * 64 + g * 16 + c] + lbuf[3 * 64 + g * 16 + c];
#pragma unroll
            for (int r = 0; r < 4; ++r) {
                float lr = __shfl(lt, quad * 4 + r, 64);
                float inv = 1.0f / lr;
                float* orow = ob + (size_t)(qt * 64 + g * 16 + quad * 4 + r) * 512;
#pragma unroll
                for (int dg = 0; dg < 4; ++dg)
                    orow[dg * 16 + c] = O[g][dg][r] * inv;
            }
        }
    }
}

// -------------------- launch --------------------
extern "C" void kernel_launch(void* const* d_in, const int* in_sizes, int n_in,
                              void* d_out, int out_size, void* d_ws, size_t ws_size,
                              hipStream_t stream) {
    const float* x = (const float*)d_in[0];   // [4,2048,512]
    const float* w = (const float*)d_in[1];   // [1536,512]
    float* out = (float*)d_out;               // [4,2048,512]

    char* ws = (char*)d_ws;
    bf16_t* xb = (bf16_t*)(ws);                       //  8 MB
    bf16_t* wb = (bf16_t*)(ws + 8388608);             //  1.5 MB
    bf16_t* q  = (bf16_t*)(ws + 9961472);             //  8 MB
    bf16_t* k  = (bf16_t*)(ws + 18350080);            //  8 MB
    bf16_t* vt = (bf16_t*)(ws + 26738688);            //  8 MB (end 33.5 MB)

    convert_kernel<<<4864, 256, 0, stream>>>(x, xb, w, wb, 1048576);
    qkv_gemm<<<1536, 256, 0, stream>>>(xb, wb, q, k, vt);
    flash_attn<<<dim3(32, 32), 256, 0, stream>>>(q, k, vt, out);
}

// Round 9
// 140.969 us; speedup vs baseline: 1.4829x; 1.0204x over previous
//
#include <hip/hip_runtime.h>
#include <hip/hip_bf16.h>
#include <stdint.h>

typedef __bf16 bf16_t;
typedef float floatx4 __attribute__((ext_vector_type(4)));
typedef __bf16 bf16x8 __attribute__((ext_vector_type(8)));
typedef __bf16 bf16x4 __attribute__((ext_vector_type(4)));
typedef unsigned int uintx4 __attribute__((ext_vector_type(4)));

// scale = DH^-0.5 * log2(e), folded into Q at GEMM epilogue so softmax uses raw exp2
#define QSCALE 0.1803368801111204f

// -------------------- async global->LDS (16B) --------------------
__device__ __forceinline__ void gl2lds16(const bf16_t* g, bf16_t* l) {
    __builtin_amdgcn_global_load_lds(
        (const __attribute__((address_space(1))) unsigned int*)g,
        (__attribute__((address_space(3))) unsigned int*)l,
        16, 0, 0);
}

// pack two f32 -> one dword of 2 bf16
__device__ __forceinline__ unsigned pk2(float lo, float hi) {
    unsigned short a = __builtin_bit_cast(unsigned short, (bf16_t)lo);
    unsigned short b = __builtin_bit_cast(unsigned short, (bf16_t)hi);
    return (unsigned)a | ((unsigned)b << 16);
}

// -------------------- fp32 -> bf16 convert (x and W fused) --------------------
__global__ __launch_bounds__(256) void convert_kernel(const float* __restrict__ x,
                                                      bf16_t* __restrict__ xb,
                                                      const float* __restrict__ w,
                                                      bf16_t* __restrict__ wb,
                                                      int nx4) {   // x chunks; W chunks follow
    int i = blockIdx.x * 256 + threadIdx.x;
    const float* in; bf16_t* out; int j;
    if (i < nx4) { in = x; out = xb; j = i; }
    else         { in = w; out = wb; j = i - nx4; }
    float4 v = ((const float4*)in)[j];
    bf16x4 o;
    o.x = (bf16_t)v.x; o.y = (bf16_t)v.y; o.z = (bf16_t)v.z; o.w = (bf16_t)v.w;
    ((bf16x4*)out)[j] = o;
}

// -------------------- QKV projection GEMM (gemm_bt) --------------------
// R10 structure (kept, current-best config): 128x64 tile, double-buffered LDS,
// one barrier per K-step, staging issued before compute, XCD swizzle.
__global__ __launch_bounds__(256, 3) void qkv_gemm(const bf16_t* __restrict__ X,   // [8192][512]
                                                   const bf16_t* __restrict__ W,   // [1536][512]
                                                   bf16_t* __restrict__ Q,         // [32][2048][64] (pre-scaled)
                                                   bf16_t* __restrict__ K,         // [32][2048][64]
                                                   bf16_t* __restrict__ Vt)        // [32][64][2048]
{
    __shared__ bf16_t As[2][128 * 64];   // 2 x 16 KB
    __shared__ bf16_t Bs[2][64 * 64];    // 2 x  8 KB   (total 48 KB -> 3 blocks/CU)

    const int tid  = threadIdx.x;
    const int wave = tid >> 6;
    const int lane = tid & 63;
    const int quad = lane >> 4;
    const int lrow = lane & 15;
    const int t7g  = lrow & 7;      // = row&7 of every fragment row this lane touches
    const int wbase = tid & 192;    // wave*64, wave-uniform

    int raw = blockIdx.x;
    int xcd = raw & 7;
    int idx = raw >> 3;
    int bx  = xcd * 8 + idx / 24;
    int by  = idx - (idx / 24) * 24;
    const int bm0 = bx * 128;
    const int bn0 = by * 64;
    const int mw = (wave >> 1) * 64;
    const int nw = (wave & 1) * 32;

    floatx4 acc[4][2];
#pragma unroll
    for (int i = 0; i < 4; i++)
#pragma unroll
        for (int j = 0; j < 2; j++) acc[i][j] = (floatx4)0.0f;

    const bf16_t* xb  = X + (size_t)bm0 * 512;
    const bf16_t* wbp = W + (size_t)bn0 * 512;
    const bf16_t* srcA[4];
    const bf16_t* srcB[2];
#pragma unroll
    for (int r = 0; r < 4; ++r) {
        int c = r * 256 + tid;
        int row = c >> 3, kc = c & 7;
        int skc = kc ^ (row & 7);              // swizzled source chunk
        srcA[r] = xb + (size_t)row * 512 + skc * 8;
    }
#pragma unroll
    for (int r = 0; r < 2; ++r) {
        int c = r * 256 + tid;
        int row = c >> 3, kc = c & 7;
        int skc = kc ^ (row & 7);
        srcB[r] = wbp + (size_t)row * 512 + skc * 8;
    }

    auto STAGE = [&](int bufI, int k0) {
#pragma unroll
        for (int r = 0; r < 4; ++r)
            gl2lds16(srcA[r] + k0, As[bufI] + (size_t)(r * 256 + wbase) * 8);
#pragma unroll
        for (int r = 0; r < 2; ++r)
            gl2lds16(srcB[r] + k0, Bs[bufI] + (size_t)(r * 256 + wbase) * 8);
    };

    STAGE(0, 0);

#pragma unroll 1
    for (int kb = 0; kb < 8; ++kb) {
        const int buf = kb & 1;
        __syncthreads();                 // drains vmcnt: tile kb staged; prev compute done
        if (kb < 7) STAGE(buf ^ 1, (kb + 1) * 64);

        const bf16_t* as = As[buf];
        const bf16_t* bs = Bs[buf];
#pragma unroll
        for (int ks = 0; ks < 2; ++ks) {
            bf16x8 af[4], bfr[2];
#pragma unroll
            for (int mi = 0; mi < 4; mi++)
                af[mi] = *(const bf16x8*)(as + (mw + mi * 16 + lrow) * 64 + (((ks * 4 + quad) ^ t7g) << 3));
#pragma unroll
            for (int ni = 0; ni < 2; ni++)
                bfr[ni] = *(const bf16x8*)(bs + (nw + ni * 16 + lrow) * 64 + (((ks * 4 + quad) ^ t7g) << 3));
            __builtin_amdgcn_s_setprio(1);
#pragma unroll
            for (int mi = 0; mi < 4; mi++)
#pragma unroll
                for (int ni = 0; ni < 2; ni++)
                    acc[mi][ni] = __builtin_amdgcn_mfma_f32_16x16x32_bf16(af[mi], bfr[ni], acc[mi][ni], 0, 0, 0);
            __builtin_amdgcn_s_setprio(0);
        }
    }

    // epilogue: C/D layout col=lane&15, row=quad*4+reg  [verified m89]
#pragma unroll
    for (int mi = 0; mi < 4; mi++) {
        int mbase = bm0 + mw + mi * 16 + quad * 4;
        int b = mbase >> 11, n = mbase & 2047;
#pragma unroll
        for (int ni = 0; ni < 2; ni++) {
            int o = bn0 + nw + ni * 16 + lrow;
            int s  = o >> 9;
            int h  = (o >> 6) & 7;
            int dh = o & 63;
            int bh = b * 8 + h;
            if (s == 2) {
                bf16x4 pv;
#pragma unroll
                for (int r = 0; r < 4; r++) pv[r] = (bf16_t)acc[mi][ni][r];
                *(bf16x4*)(Vt + ((size_t)bh * 64 + dh) * 2048 + n) = pv;   // 8B packed
            } else if (s == 0) {
#pragma unroll
                for (int r = 0; r < 4; r++)
                    Q[((size_t)bh * 2048 + n + r) * 64 + dh] = (bf16_t)(acc[mi][ni][r] * QSCALE);
            } else {
#pragma unroll
                for (int r = 0; r < 4; r++)
                    K[((size_t)bh * 2048 + n + r) * 64 + dh] = (bf16_t)acc[mi][ni][r];
            }
        }
    }
}

// -------------------- flash attention --------------------
// R13: byte-identical revert to R8 (proven 55.6us — empirical optimum across
// R5/R6/R7/R9/R10/R11/R12 variants). No XCD swizzle (R10 A/B: swizzle costs
// ~2.6us here despite 5.7x FETCH cut — staging latency was already hidden).
// R12 lesson: halving LDS reads via pair-tiles LOST 5us to exposed staging +
// occupancy; flash is chain/convoy-bound, not LDS-read-bound.
__device__ __forceinline__ void stage_tile(const bf16_t* __restrict__ kb,
                                           const bf16_t* __restrict__ vb,
                                           int kt, bf16_t* ksbuf, bf16_t* vsbuf,
                                           int wave, int lane) {
#pragma unroll
    for (int part = 0; part < 2; ++part) {
        int ch  = part * 256 + wave * 64 + lane;   // chunk id 0..511
        int row = ch >> 3, cc = ch & 7;
        int scc = cc ^ (row & 7);                  // swizzled source chunk
        bf16_t* ldst = ksbuf + (size_t)(part * 256 + wave * 64) * 8;  // wave-uniform
        gl2lds16(kb + ((size_t)(kt * 64 + row)) * 64 + scc * 8, ldst);
        bf16_t* ldst2 = vsbuf + (size_t)(part * 256 + wave * 64) * 8;
        gl2lds16(vb + (size_t)row * 2048 + kt * 64 + scc * 8, ldst2);
    }
}

__global__ __launch_bounds__(256, 5) void flash_attn(const bf16_t* __restrict__ Q,   // [32][2048][64], pre-scaled
                                                     const bf16_t* __restrict__ K,   // [32][2048][64]
                                                     const bf16_t* __restrict__ Vt,  // [32][64][2048]
                                                     float* __restrict__ Out)        // [4][2048][512]
{
    __shared__ bf16_t Ks[2][64 * 64];   // 16 KB
    __shared__ bf16_t Vs[2][64 * 64];   // 16 KB
    // total 32768 B -> 5 blocks/CU, 20 waves/CU

    const int tid  = threadIdx.x;
    const int wave = tid >> 6;
    const int lane = tid & 63;
    const int quad = lane >> 4;
    const int c    = lane & 15;
    const int t7   = c & 7;
    const int qhalf = wave >> 1;   // which 32 q-rows
    const int khalf = wave & 1;    // which 32 keys of each 64-key tile
    const int qt = blockIdx.x;
    const int bh = blockIdx.y;
    const int b = bh >> 3, h = bh & 7;

    // K A-operand row map: m=c -> key row bw = quad-bit-swapped c (bijective 0..15)
    const int bw    = ((c & 4) << 1) | ((c & 8) >> 1) | (c & 3);
    const int brow7 = bw & 7;

    // Q fragments (B-operand: n=lane&15=q-col, k=quad*8+j), shifted-query source row.
    bf16x8 qf[2][2];
#pragma unroll
    for (int mt = 0; mt < 2; ++mt) {
        int qg  = qt * 64 + qhalf * 32 + mt * 16 + c;
        int src = (qg == 0) ? 0 : qg - 1;
        const bf16_t* qbase = Q + ((size_t)bh * 2048 + src) * 64;
        qf[mt][0] = *(const bf16x8*)(qbase + quad * 8);
        qf[mt][1] = *(const bf16x8*)(qbase + 32 + quad * 8);
    }

    floatx4 o[2][4];
#pragma unroll
    for (int mt = 0; mt < 2; ++mt)
#pragma unroll
        for (int i = 0; i < 4; i++) o[mt][i] = (floatx4)0.0f;
    float lacc[2] = {0.f, 0.f};

    const bf16_t* kb = K + ((size_t)bh * 2048) * 64;
    const bf16_t* vb = Vt + ((size_t)bh * 64) * 2048;

    stage_tile(kb, vb, 0, Ks[0], Vs[0], wave, lane);

#pragma unroll 1
    for (int kt = 0; kt < 32; ++kt) {
        const int buf = kt & 1;
        __syncthreads();   // drains vmcnt: tile kt ready; all waves done reading buf^1
        if (kt < 31)
            stage_tile(kb, vb, kt + 1, Ks[buf ^ 1], Vs[buf ^ 1], wave, lane);

        const bf16_t* ks = Ks[buf];
        const bf16_t* vs = Vs[buf];

        // S^T = K * Q^T : D[key=quad*4+r][q=c]; K rows via bw map.
        floatx4 s[2][2];
        __builtin_amdgcn_s_setprio(1);
#pragma unroll
        for (int nt = 0; nt < 2; ++nt) {
            const bf16_t* krow = ks + (khalf * 32 + nt * 16 + bw) * 64;
            bf16x8 kf0 = *(const bf16x8*)(krow + ((quad ^ brow7) << 3));
            bf16x8 kf1 = *(const bf16x8*)(krow + (((4 + quad) ^ brow7) << 3));
#pragma unroll
            for (int mt = 0; mt < 2; ++mt) {
                floatx4 t = (floatx4)0.0f;
                t = __builtin_amdgcn_mfma_f32_16x16x32_bf16(kf0, qf[mt][0], t, 0, 0, 0);
                t = __builtin_amdgcn_mfma_f32_16x16x32_bf16(kf1, qf[mt][1], t, 0, 0, 0);
                s[mt][nt] = t;
            }
        }
        __builtin_amdgcn_s_setprio(0);

        // P = exp2(S); per-lane partial row sum (q=c); in-register PV A-frags
        bf16x8 pfrag[2];
#pragma unroll
        for (int mt = 0; mt < 2; ++mt) {
            float pe[2][4];
#pragma unroll
            for (int nt = 0; nt < 2; ++nt)
#pragma unroll
                for (int r = 0; r < 4; ++r) {
                    float p = __builtin_amdgcn_exp2f(s[mt][nt][r]);
                    lacc[mt] += p;
                    pe[nt][r] = p;
                }
            unsigned A0 = pk2(pe[0][0], pe[0][1]);
            unsigned A1 = pk2(pe[0][2], pe[0][3]);
            unsigned B0 = pk2(pe[1][0], pe[1][1]);
            unsigned B1 = pk2(pe[1][2], pe[1][3]);
            auto r0 = __builtin_amdgcn_permlane32_swap((int)A0, (int)B0, false, false);
            auto r1 = __builtin_amdgcn_permlane32_swap((int)A1, (int)B1, false, false);
            uintx4 fd;
            fd.x = (unsigned)r0[0];
            fd.y = (unsigned)r1[0];
            fd.z = (unsigned)r0[1];
            fd.w = (unsigned)r1[1];
            pfrag[mt] = __builtin_bit_cast(bf16x8, fd);
        }

        // O += P * V (contraction over this wave's 32 keys, A-frag in registers)
        __builtin_amdgcn_s_setprio(1);
#pragma unroll
        for (int sub = 0; sub < 4; ++sub) {
            const bf16_t* vrow = vs + (sub * 16 + c) * 64;      // row&7 == t7
            bf16x8 vf = *(const bf16x8*)(vrow + (((khalf * 4 + quad) ^ t7) << 3));
            o[0][sub] = __builtin_amdgcn_mfma_f32_16x16x32_bf16(pfrag[0], vf, o[0][sub], 0, 0, 0);
            o[1][sub] = __builtin_amdgcn_mfma_f32_16x16x32_bf16(pfrag[1], vf, o[1][sub], 0, 0, 0);
        }
        __builtin_amdgcn_s_setprio(0);
    }

    // in-wave reduction over the 4 key-quads: butterfly xor16 + xor32
#pragma unroll
    for (int mt = 0; mt < 2; ++mt) {
        lacc[mt] += __shfl_xor(lacc[mt], 16, 64);
        lacc[mt] += __shfl_xor(lacc[mt], 32, 64);
    }

    // cross-khalf reduction of partial O and l via LDS (once)
    __syncthreads();                 // all tile reads done; Ks/Vs reusable
    float* obuf = (float*)Ks;        // 2 qhalf x 2048 f32 = 16 KB
    float* lbuf = (float*)Vs;        // 2 qhalf x 32 f32
    if (khalf == 1) {
#pragma unroll
        for (int mt = 0; mt < 2; ++mt)
#pragma unroll
            for (int sub = 0; sub < 4; ++sub)
                *(floatx4*)(obuf + qhalf * 2048 + (mt * 4 + sub) * 256 + lane * 4) = o[mt][sub];
        if (lane < 16) {             // quad0 lanes: lacc holds l(q = mt*16+c)
#pragma unroll
            for (int mt = 0; mt < 2; ++mt)
                lbuf[qhalf * 32 + mt * 16 + c] = lacc[mt];
        }
    }
    __syncthreads();
    if (khalf == 0) {
#pragma unroll
        for (int mt = 0; mt < 2; ++mt)
#pragma unroll
            for (int sub = 0; sub < 4; ++sub)
                o[mt][sub] += *(const floatx4*)(obuf + qhalf * 2048 + (mt * 4 + sub) * 256 + lane * 4);
#pragma unroll
        for (int mt = 0; mt < 2; ++mt)
            lacc[mt] += lbuf[qhalf * 32 + mt * 16 + c];

        // epilogue: out[b][n][h*64 + d] = o / l ; l for row q=quad*4+r via shfl
        float* ob = Out + (size_t)b * 2048 * 512 + (size_t)h * 64;
#pragma unroll
        for (int mt = 0; mt < 2; ++mt) {
            int n0 = qt * 64 + qhalf * 32 + mt * 16 + quad * 4;
#pragma unroll
            for (int r = 0; r < 4; r++) {
                float lr = __shfl(lacc[mt], quad * 4 + r, 64);
                float inv = 1.0f / lr;
                float* orow = ob + (size_t)(n0 + r) * 512;
#pragma unroll
                for (int sub = 0; sub < 4; ++sub)
                    orow[sub * 16 + c] = o[mt][sub][r] * inv;
            }
        }
    }
}

// -------------------- launch --------------------
extern "C" void kernel_launch(void* const* d_in, const int* in_sizes, int n_in,
                              void* d_out, int out_size, void* d_ws, size_t ws_size,
                              hipStream_t stream) {
    const float* x = (const float*)d_in[0];   // [4,2048,512]
    const float* w = (const float*)d_in[1];   // [1536,512]
    float* out = (float*)d_out;               // [4,2048,512]

    char* ws = (char*)d_ws;
    bf16_t* xb = (bf16_t*)(ws);                       //  8 MB
    bf16_t* wb = (bf16_t*)(ws + 8388608);             //  1.5 MB
    bf16_t* q  = (bf16_t*)(ws + 9961472);             //  8 MB
    bf16_t* k  = (bf16_t*)(ws + 18350080);            //  8 MB
    bf16_t* vt = (bf16_t*)(ws + 26738688);            //  8 MB (end 33.5 MB)

    convert_kernel<<<4864, 256, 0, stream>>>(x, xb, w, wb, 1048576);
    qkv_gemm<<<1536, 256, 0, stream>>>(xb, wb, q, k, vt);
    flash_attn<<<dim3(32, 32), 256, 0, stream>>>(q, k, vt, out);
}